// Round 1
// 206.339 us; speedup vs baseline: 1.0470x; 1.0470x over previous
//
#include <hip/hip_runtime.h>

#define BS      4096
#define SEGLEN  8192
#define LAMBDA1 8e-05f
#define LAMBDA2 8e-05f

typedef float f4 __attribute__((ext_vector_type(4)));

// ---------------------------------------------------------------------------
// Kernel 1: per-row stats. One block (256 threads) per row.
//   smooth[row] = sum_{c=0..SEGLEN-2} (s[c+1]-s[c])^2
//   spars [row] = sum_c s[c]
//   ms    [row] = argmax_c s[c]   (FIRST occurrence on ties, like np.argmax)
//
// This revision halves the VMEM instruction count vs the previous version:
// the old code issued one strided global_load_dword per float4 group to get
// the "next" element for the boundary diff. Now the boundary value comes
// from __shfl_down (lane+1's v.x, same k) and a tiny 4x8 LDS table for the
// wave-boundary lanes (lane 63) and the k-boundary (t=255). 8 nontemporal
// global_load_dwordx4 per thread are the ONLY global reads — streaming data
// with zero reuse, so nt (bypass cache pollution) is free.
// ---------------------------------------------------------------------------
__global__ __launch_bounds__(256) void row_stats(const float* __restrict__ scores,
                                                 float* __restrict__ smooth,
                                                 float* __restrict__ spars,
                                                 int*   __restrict__ ms,
                                                 float* __restrict__ out) {
    const int row = blockIdx.x;
    const float* __restrict__ s = scores + (size_t)row * SEGLEN;
    const int t    = threadIdx.x;
    const int wave = t >> 6;
    const int lane = t & 63;

    // kernel-2 atomicAdds into out; zero it here (stream order + kernel
    // boundary release make this coherent).
    if (row == 0 && t == 0) out[0] = 0.0f;

    // SEGLEN/4 float4s, 256 threads -> 8 per thread, coalesced, nontemporal.
    f4 v[8];
    #pragma unroll
    for (int k = 0; k < 8; ++k)
        v[k] = __builtin_nontemporal_load(((const f4*)s) + (t + k * 256));

    // Boundary table: sx[w][k] = v.x of lane 0 of wave w at iteration k.
    //   lane 63 of wave w (w<3), iter k : next element = sx[w+1][k]
    //   lane 63 of wave 3,       iter k : next element = sx[0][k+1] (k<7)
    //   t=255, k=7 (last element of row): no diff -> use v.w (d3 = 0)
    __shared__ float sx[4][8];
    if (lane == 0) {
        #pragma unroll
        for (int k = 0; k < 8; ++k) sx[wave][k] = v[k].x;
    }
    __syncthreads();

    float sum  = 0.0f;
    float sq   = 0.0f;
    float mval = -1.0f;   // scores are uniform [0,1): any real score beats -1
    int   midx = SEGLEN;

    #pragma unroll
    for (int k = 0; k < 8; ++k) {
        const int c0  = (t + k * 256) * 4;     // element index of v[k].x
        float nxt = __shfl_down(v[k].x, 1);    // lane+1's first element, same k
        if (lane == 63)
            nxt = (wave < 3) ? sx[wave + 1][k]
                             : ((k < 7) ? sx[0][k + 1] : v[k].w);

        const float d0 = v[k].y - v[k].x;
        const float d1 = v[k].z - v[k].y;
        const float d2 = v[k].w - v[k].z;
        const float d3 = nxt    - v[k].w;
        sq  += d0 * d0 + d1 * d1 + d2 * d2 + d3 * d3;
        sum += v[k].x + v[k].y + v[k].z + v[k].w;

        // strictly-greater keeps FIRST index (per-thread indices increase with k)
        if (v[k].x > mval) { mval = v[k].x; midx = c0;     }
        if (v[k].y > mval) { mval = v[k].y; midx = c0 + 1; }
        if (v[k].z > mval) { mval = v[k].z; midx = c0 + 2; }
        if (v[k].w > mval) { mval = v[k].w; midx = c0 + 3; }
    }

    // wave64 butterfly reduction
    #pragma unroll
    for (int off = 32; off > 0; off >>= 1) {
        sum += __shfl_xor(sum, off);
        sq  += __shfl_xor(sq,  off);
        const float ov = __shfl_xor(mval, off);
        const int   oi = __shfl_xor(midx, off);
        if (ov > mval || (ov == mval && oi < midx)) { mval = ov; midx = oi; }
    }

    __shared__ float ssum[4], ssq[4], smv[4];
    __shared__ int   smi[4];
    if (lane == 0) { ssum[wave] = sum; ssq[wave] = sq; smv[wave] = mval; smi[wave] = midx; }
    __syncthreads();

    if (t == 0) {
        #pragma unroll
        for (int w = 1; w < 4; ++w) {
            sum += ssum[w];
            sq  += ssq[w];
            if (smv[w] > mval || (smv[w] == mval && smi[w] < midx)) { mval = smv[w]; midx = smi[w]; }
        }
        spars [row] = sum;
        smooth[row] = sq;
        ms    [row] = midx;
    }
}

// ---------------------------------------------------------------------------
// Kernel 2: margin + masked final sum. 256 blocks x 256 threads.
// Block b owns i in [b*16, b*16+16). ms[] and labels[] staged in LDS (32 KB).
// Grand sum over (i pos, j neg) pairs of relu(1 - ms[i] + ms[j]) plus the
// lambda terms for pos i; one float atomicAdd per block.
// Per-block int32 bound: 16 * 4096 * 8192 = 5.4e8 < INT_MAX.
// ---------------------------------------------------------------------------
#define MB_BLOCKS 256
#define IPB (BS / MB_BLOCKS)   // 16 rows per block

__global__ __launch_bounds__(256) void margin_final(const float* __restrict__ smooth,
                                                    const float* __restrict__ spars,
                                                    const int*   __restrict__ ms,
                                                    const int*   __restrict__ labels,
                                                    float*       __restrict__ out) {
    __shared__ int ms_l[BS];
    __shared__ int lab_l[BS];

    const int t = threadIdx.x;
    const int b = blockIdx.x;

    for (int idx = t; idx < BS; idx += 256) {
        ms_l[idx]  = ms[idx];
        lab_l[idx] = labels[idx];
    }
    __syncthreads();

    int   macc = 0;    // hinge sum over this block's pos-i rows
    float facc = 0.0f; // lambda terms for this block's pos-i rows

    #pragma unroll
    for (int ii = 0; ii < IPB; ++ii) {
        const int i = b * IPB + ii;
        if (lab_l[i] == 1) {
            const int base = 1 - ms_l[i];
            for (int j = t; j < BS; j += 256) {
                if (lab_l[j] == 0) {
                    const int v = base + ms_l[j];
                    macc += (v > 0) ? v : 0;
                }
            }
        }
    }
    if (t < IPB) {
        const int i = b * IPB + t;
        if (lab_l[i] == 1)
            facc = LAMBDA1 * smooth[i] + LAMBDA2 * spars[i];
    }

    // block reduction
    #pragma unroll
    for (int off = 32; off > 0; off >>= 1) {
        macc += __shfl_xor(macc, off);
        facc += __shfl_xor(facc, off);
    }
    __shared__ int   sacc[4];
    __shared__ float sfac[4];
    const int wave = t >> 6;
    if ((t & 63) == 0) { sacc[wave] = macc; sfac[wave] = facc; }
    __syncthreads();

    if (t == 0) {
        macc += sacc[1] + sacc[2] + sacc[3];
        facc += sfac[1] + sfac[2] + sfac[3];
        const float partial = (facc + (float)macc) * (1.0f / (float)BS);
        if (partial != 0.0f) atomicAdd(out, partial);
    }
}

extern "C" void kernel_launch(void* const* d_in, const int* in_sizes, int n_in,
                              void* d_out, int out_size, void* d_ws, size_t ws_size,
                              hipStream_t stream) {
    const float* scores = (const float*)d_in[0];
    const int*   labels = (const int*)d_in[1];
    float*       out    = (float*)d_out;

    float* smooth = (float*)d_ws;
    float* spars  = smooth + BS;
    int*   ms     = (int*)(spars + BS);

    row_stats<<<BS, 256, 0, stream>>>(scores, smooth, spars, ms, out);
    margin_final<<<MB_BLOCKS, 256, 0, stream>>>(smooth, spars, ms, labels, out);
}